// Round 9
// baseline (119.788 us; speedup 1.0000x reference)
//
#include <hip/hip_runtime.h>

#define B_    2
#define T_    400
#define NCH_  8
#define NBIN_ 512
#define NBAND_ 40
#define NPV_  64

using short8  = __attribute__((ext_vector_type(8))) short;
using float4v = __attribute__((ext_vector_type(4))) float;

// bf16 round-to-nearest-even pack of two floats into one dword (lo=x, hi=y)
static __device__ inline unsigned pkbf(float x, float y) {
  union { float f; unsigned u; } a, b;
  a.f = x; b.f = y;
  unsigned ra = a.u + 0x7fffu + ((a.u >> 16) & 1u);
  unsigned rb = b.u + 0x7fffu + ((b.u >> 16) & 1u);
  return (ra >> 16) | (rb & 0xffff0000u);
}
// unpack bf16 pair dword -> two f32 (lo, hi)
static __device__ inline void upk(unsigned u, float& lo, float& hi) {
  union { unsigned q; float f; } a, b;
  a.q = u << 16; b.q = u & 0xffff0000u;
  lo = a.f; hi = b.f;
}
// {lo:ar, hi:-ai} -> {lo:ai, hi:ar}
static __device__ inline unsigned swapvar(unsigned u) {
  unsigned r = u ^ 0x80000000u;
  return (r >> 16) | (r << 16);
}
// async global->LDS DMA, 16 B per lane (CK amd_direct_load pattern; m97-verified width)
static __device__ inline void gld_lds16(const uint4* g, uint4* l) {
  auto* lds_ptr = reinterpret_cast<__attribute__((address_space(3))) uint4*>(
      reinterpret_cast<uintptr_t>(l));
  auto* g_ptr = reinterpret_cast<const __attribute__((address_space(1))) uint4*>(
      reinterpret_cast<uintptr_t>(g));
  __builtin_amdgcn_global_load_lds(g_ptr, lds_ptr, 16, 0, 0);
}

// ws layout (bytes):
//   [0..159]              : dsinv[40] floats
//   [1024, 1024+98304)    : band B-frags, s-major, stored ONCE (N=48):
//                           F=(s*3+n)*64+lane, uint4; dword t = {bmr[f,k], bmi[f,k]},
//                           f = s*16 + (lane>>4)*4 + t, k = n*16 + (lane&15)
//   [197632, 197632+16384): epi B-frags: E=(nt*4+ks)*64+lane, uint4 each
__global__ __launch_bounds__(256) void pv_prep(
    const float* __restrict__ bmr, const float* __restrict__ bmi,
    const float* __restrict__ c2pr, const float* __restrict__ c2pi,
    float* __restrict__ ws)
{
  const int tid = threadIdx.x;
  const int blk = blockIdx.x;
  if (blk == 0) {
    __shared__ float sds[256];
    int k = tid & 63, part = tid >> 6;
    float s = 0.f;
    if (k < NBAND_) {
      const float* col = bmr + k;
      #pragma unroll 16
      for (int f = part * 128; f < part * 128 + 128; f++) s += col[f * 40];
    }
    sds[tid] = s;
    __syncthreads();
    if (tid < NBAND_) {
      float t = sds[tid] + sds[tid + 64] + sds[tid + 128] + sds[tid + 192];
      ws[tid] = 1.0f / fmaxf(t, 1e-20f);
    }
  } else if (blk <= 24) {
    int F = (blk - 1) * 256 + tid;     // 0..6143
    int l = F & 63;
    int fid = F >> 6;                  // 0..95 = s*3 + n
    int s5 = fid / 3;
    int n = fid - s5 * 3;
    int k = n * 16 + (l & 15);
    int quad = l >> 4;
    unsigned dw[4];
    #pragma unroll
    for (int t2 = 0; t2 < 4; t2++) {
      float v0 = 0.f, v1 = 0.f;
      if (k < NBAND_) {
        int f = s5 * 16 + quad * 4 + t2;
        v0 = bmr[f * 40 + k]; v1 = bmi[f * 40 + k];
      }
      dw[t2] = pkbf(v0, v1);
    }
    ((uint4*)((char*)ws + 1024))[F] = make_uint4(dw[0], dw[1], dw[2], dw[3]);
  } else {
    int F2 = (blk - 25) * 256 + tid;   // 0..1023
    int lane = F2 & 63, E = F2 >> 6;
    int nt = E >> 2, ks = E & 3;
    int n = lane & 15, quad = lane >> 4;
    int p = nt * 16 + n;
    unsigned dw[4];
    #pragma unroll
    for (int t2 = 0; t2 < 4; t2++) {
      int c = ks * 16 + quad * 4 + t2;
      dw[t2] = pkbf(c2pr[p * 64 + c], -c2pi[p * 64 + c]);
    }
    ((uint4*)((char*)ws + 197632))[E * 64 + lane] = make_uint4(dw[0], dw[1], dw[2], dw[3]);
  }
}

// LDS dwords (total 10240 dw = 40,960 B exactly -> 4 blocks/CU, all 800 resident):
//   vsh  uint[8][512] @0      (16,384 B)  -- epilogue overlay: bcsh uint[48][68]
//   bst  uint4[2][768] @4096  (24,576 B)  -- B-frag double buffer (4 K-steps each)
__global__ __launch_bounds__(256, 4) void pv_main(
    const float* __restrict__ br, const float* __restrict__ bi,
    const float* __restrict__ ws, float* __restrict__ out)
{
  __shared__ __align__(16) unsigned smem[10240];
  unsigned* vsh = smem;                      // [8][512] bf16-pair
  uint4*    bst = (uint4*)(smem + 4096);     // [2][768]

  const int bt  = blockIdx.x;
  const int tid = threadIdx.x;
  const float* pr  = br + (size_t)bt * (NCH_ * NBIN_);
  const float* pim = bi + (size_t)bt * (NCH_ * NBIN_);

  const int mt   = tid >> 6;       // wave id = M-tile
  const int lane = tid & 63;
  const int m16  = lane & 15;
  const int quad = lane >> 4;
  const int p    = mt * 16 + m16;
  const int ich  = p >> 3, jch = p & 7;
  const uint4* BF0 = (const uint4*)((const char*)ws + 1024);

  // ---- stage 0 DMA issued first: lands under phase A's compute ----
  {
    const uint4* g = BF0 + tid;
    uint4* l = bst + tid;
    gld_lds16(g, l);
    gld_lds16(g + 256, l + 256);
    gld_lds16(g + 512, l + 512);
  }

  // ---- phase A: 2 bins per thread -> vsh (bf16 pairs, stride 512) ----
  #pragma unroll
  for (int fs = 0; fs < 2; fs++) {
    const int f = fs * 256 + tid;
    const int fm = (f == 0) ? 0 : ((f == 511) ? 509 : f - 1);
    const int fp = (f == 0) ? 2 : ((f == 511) ? 511 : f + 1);
    float tr = 0.f;
    float t1[8], t2[8];
    #pragma unroll
    for (int c = 0; c < 8; c++) {
      const float* cr = pr + c * 512;
      const float* ci = pim + c * 512;
      float xr = cr[f],   xi = ci[f];
      float xrm = cr[fm], xim = ci[fm];
      float xrp = cr[fp], xip = ci[fp];
      tr = fmaf(xr, xr, tr); tr = fmaf(xi, xi, tr);
      float Gr = fmaf(xrm, xrp,  xim * xip);
      float Gi = fmaf(xrm, xip, -(xim * xrp));
      float am = fmaxf(fmaxf(fabsf(Gr), fabsf(Gi)), 1e-30f);
      float rc = __builtin_amdgcn_rcpf(am);
      float q1 = Gr * rc, q2 = Gi * rc;
      float n2 = fmaf(q1, q1, q2 * q2);
      float rn = __builtin_amdgcn_rsqf(n2);
      bool ok = n2 > 0.f;
      float ur = ok ? q1 * rn : 1.f;
      float ui = ok ? q2 * rn : 0.f;
      float mg = __builtin_amdgcn_sqrtf(fmaf(xr, xr, xi * xi));
      t1[c] = mg * ur; t2[c] = mg * ui;
    }
    float scv = __builtin_amdgcn_rsqf(fmaxf(tr, 1e-20f));
    #pragma unroll
    for (int c = 0; c < 8; c++)
      vsh[c * 512 + f] = pkbf(t1[c] * scv, t2[c] * scv);
  }
  __syncthreads();               // vsh ready AND stage-0 DMA drained

  // ---- band GEMM: 8 stages x 4 K-steps, B double-buffered in LDS ----
  const uint4* Avp = (const uint4*)(vsh + ich * 512) + quad;
  const uint4* Bvp = (const uint4*)(vsh + jch * 512) + quad;

  float4v acc[6];                // [0..2]=real cols, [3..5]=imag cols
  #pragma unroll
  for (int g = 0; g < 6; g++) acc[g] = (float4v){0.f, 0.f, 0.f, 0.f};

  for (int st = 0; st < 8; st++) {
    if (st < 7) {                // DMA next stage into the other buffer
      const uint4* g = BF0 + (st + 1) * 768 + tid;
      uint4* l = bst + ((st + 1) & 1) * 768 + tid;
      gld_lds16(g, l);
      gld_lds16(g + 256, l + 256);
      gld_lds16(g + 512, l + 512);
    }
    const uint4* bb = bst + (st & 1) * 768;
    #pragma unroll
    for (int q = 0; q < 4; q++) {
      const int s = st * 4 + q;
      uint4 av = Avp[s * 4];
      uint4 bv = Bvp[s * 4];
      uint4 cb0 = bb[(q * 3 + 0) * 64 + lane];
      uint4 cb1 = bb[(q * 3 + 1) * 64 + lane];
      uint4 cb2 = bb[(q * 3 + 2) * 64 + lane];
      float ar[4], ai[4];
      {
        float vr, vi, wr, wi;
        upk(av.x, vr, vi); upk(bv.x, wr, wi);
        ar[0] = fmaf(vr, wr,  vi * wi); ai[0] = fmaf(vi, wr, -(vr * wi));
        upk(av.y, vr, vi); upk(bv.y, wr, wi);
        ar[1] = fmaf(vr, wr,  vi * wi); ai[1] = fmaf(vi, wr, -(vr * wi));
        upk(av.z, vr, vi); upk(bv.z, wr, wi);
        ar[2] = fmaf(vr, wr,  vi * wi); ai[2] = fmaf(vi, wr, -(vr * wi));
        upk(av.w, vr, vi); upk(bv.w, wr, wi);
        ar[3] = fmaf(vr, wr,  vi * wi); ai[3] = fmaf(vi, wr, -(vr * wi));
      }
      uint4 au1 = make_uint4(pkbf(ar[0], -ai[0]), pkbf(ar[1], -ai[1]),
                             pkbf(ar[2], -ai[2]), pkbf(ar[3], -ai[3]));
      uint4 au2 = make_uint4(swapvar(au1.x), swapvar(au1.y),
                             swapvar(au1.z), swapvar(au1.w));
      short8 af1 = __builtin_bit_cast(short8, au1);
      short8 af2 = __builtin_bit_cast(short8, au2);
      short8 b0 = __builtin_bit_cast(short8, cb0);
      short8 b1 = __builtin_bit_cast(short8, cb1);
      short8 b2 = __builtin_bit_cast(short8, cb2);
      acc[0] = __builtin_amdgcn_mfma_f32_16x16x32_bf16(af1, b0, acc[0], 0, 0, 0);
      acc[3] = __builtin_amdgcn_mfma_f32_16x16x32_bf16(af2, b0, acc[3], 0, 0, 0);
      acc[1] = __builtin_amdgcn_mfma_f32_16x16x32_bf16(af1, b1, acc[1], 0, 0, 0);
      acc[4] = __builtin_amdgcn_mfma_f32_16x16x32_bf16(af2, b1, acc[4], 0, 0, 0);
      acc[2] = __builtin_amdgcn_mfma_f32_16x16x32_bf16(af1, b2, acc[2], 0, 0, 0);
      acc[5] = __builtin_amdgcn_mfma_f32_16x16x32_bf16(af2, b2, acc[5], 0, 0, 0);
    }
    __syncthreads();             // drains next-stage DMA; guards buffer reuse
  }

  // ---- epilogue GEMM: pv[k][p] = Re(sum_c c2p[p][c]*bc[k][c]) ----
  const uint4* EF = ((const uint4*)((const char*)ws + 197632)) + (mt * 4) * 64 + lane;
  uint4 eb[4];
  #pragma unroll
  for (int ks = 0; ks < 4; ks++) eb[ks] = EF[ks * 64];

  unsigned* bcsh = smem;              // [48][68] bf16-pair, overlays vsh
  #pragma unroll
  for (int n = 0; n < 3; n++) {
    uint4 w4 = make_uint4(pkbf(acc[n][0], acc[n + 3][0]),
                          pkbf(acc[n][1], acc[n + 3][1]),
                          pkbf(acc[n][2], acc[n + 3][2]),
                          pkbf(acc[n][3], acc[n + 3][3]));
    *(uint4*)(bcsh + (n * 16 + m16) * 68 + mt * 16 + quad * 4) = w4;
  }
  __syncthreads();

  float4v eacc[3];
  #pragma unroll
  for (int kt = 0; kt < 3; kt++) eacc[kt] = (float4v){0.f, 0.f, 0.f, 0.f};
  #pragma unroll
  for (int ks = 0; ks < 4; ks++) {
    short8 bfr = __builtin_bit_cast(short8, eb[ks]);
    #pragma unroll
    for (int kt = 0; kt < 3; kt++) {
      uint4 a4 = *(const uint4*)(bcsh + (kt * 16 + m16) * 68 + ks * 16 + quad * 4);
      short8 afr = __builtin_bit_cast(short8, a4);
      eacc[kt] = __builtin_amdgcn_mfma_f32_16x16x32_bf16(afr, bfr, eacc[kt], 0, 0, 0);
    }
  }
  float* op = out + (size_t)bt * (NBAND_ * NPV_);
  const float4* wsd = (const float4*)ws;   // dsinv[40] (k>=40 lanes read pad, not stored)
  #pragma unroll
  for (int kt = 0; kt < 3; kt++) {
    float4 dv = wsd[kt * 4 + quad];
    float dva[4] = {dv.x, dv.y, dv.z, dv.w};
    #pragma unroll
    for (int r = 0; r < 4; r++) {
      int k = kt * 16 + quad * 4 + r;
      if (k < NBAND_)
        op[k * 64 + mt * 16 + m16] = eacc[kt][r] * dva[r];
    }
  }
}

// ---------------- IIR: chunked scan, 320 blocks x 256 thr, chunk=25 ----------------
__global__ __launch_bounds__(256) void pv_iir3(float* __restrict__ z,
                                               const float* __restrict__ tau)
{
  __shared__ float gsh[16][16];
  const int pg = blockIdx.x & 3;
  const int bk = blockIdx.x >> 2;
  const int k = bk % NBAND_;
  const int b = bk / NBAND_;
  const float a  = tau[k];
  const float om = 1.0f - a;
  const int c  = threadIdx.x >> 4;
  const int pl = threadIdx.x & 15;
  const int p  = pg * 16 + pl;
  const size_t stride = (size_t)NBAND_ * 64;
  size_t idx0 = (size_t)b * (T_ * NBAND_ * 64) + (size_t)(c * 25) * stride + k * 64 + p;

  float y[25];
  float accv = 0.f;
  #pragma unroll
  for (int i = 0; i < 25; i++) {
    float v = z[idx0 + (size_t)i * stride];
    accv = fmaf(a, accv, om * v);
    y[i] = accv;
  }
  gsh[c][pl] = accv;
  __syncthreads();
  float a2 = a * a, a8 = a2 * a2 * a2 * a2, a16 = a8 * a8;
  float A = a16 * a8 * a;                   // a^25
  float H = 0.f;
  #pragma unroll
  for (int d = 0; d < 15; d++) {
    if (d < c) H = fmaf(A, H, gsh[d][pl]);
  }
  float wp = a;
  #pragma unroll
  for (int i = 0; i < 25; i++) {
    z[idx0 + (size_t)i * stride] = fmaf(wp, H, y[i]);
    wp *= a;
  }
}

extern "C" void kernel_launch(void* const* d_in, const int* in_sizes, int n_in,
                              void* d_out, int out_size, void* d_ws, size_t ws_size,
                              hipStream_t stream)
{
  const float* br   = (const float*)d_in[0];
  const float* bi   = (const float*)d_in[1];
  const float* bmr  = (const float*)d_in[2];
  const float* bmi  = (const float*)d_in[3];
  const float* c2pr = (const float*)d_in[4];
  const float* c2pi = (const float*)d_in[5];
  const float* tau  = (const float*)d_in[6];
  float* out = (float*)d_out;
  float* ws  = (float*)d_ws;

  hipLaunchKernelGGL(pv_prep, dim3(29), dim3(256), 0, stream,
                     bmr, bmi, c2pr, c2pi, ws);
  hipLaunchKernelGGL(pv_main, dim3(B_ * T_), dim3(256), 0, stream,
                     br, bi, ws, out);
  hipLaunchKernelGGL(pv_iir3, dim3(B_ * NBAND_ * 4), dim3(256), 0, stream,
                     out, tau);
}

// Round 10
// 114.001 us; speedup vs baseline: 1.0508x; 1.0508x over previous
//
#include <hip/hip_runtime.h>
#include <hip/hip_fp16.h>

#define B_    2
#define T_    400
#define NCH_  8
#define NBIN_ 512
#define NBAND_ 40
#define NPV_  64

using half8   = __attribute__((ext_vector_type(8))) _Float16;
using float4v = __attribute__((ext_vector_type(4))) float;

// pack two floats into fp16 pair dword (lo=x, hi=y), RNE
static __device__ inline unsigned pkhf(float x, float y) {
  __half2 h = __float22half2_rn(make_float2(x, y));
  return __builtin_bit_cast(unsigned, h);
}
static __device__ inline unsigned rot16(unsigned u) {
  return (u >> 16) | (u << 16);
}
// packed complex multiply a = v_i * conj(v_j); dwords are (lo=re, hi=im)
static __device__ inline unsigned cmulc(unsigned viu, unsigned vju) {
  __half2 Vi = __builtin_bit_cast(__half2, viu);
  __half2 Vj = __builtin_bit_cast(__half2, vju);
  __half2 P1 = __hmul2(Vi, __low2half2(Vj));          // (vr_i*vr_j, vi_i*vr_j)
  __half2 Qi = __lowhigh2highlow(Vi);                 // (vi_i, vr_i)
  unsigned tn = __builtin_bit_cast(unsigned, __high2half2(Vj)) ^ 0x80000000u; // (vi_j, -vi_j)
  __half2 a  = __hfma2(Qi, __builtin_bit_cast(__half2, tn), P1); // (ar, ai)
  return __builtin_bit_cast(unsigned, a);
}
// async global->LDS DMA, 16 B per lane
static __device__ inline void gld_lds16(const uint4* g, uint4* l) {
  auto* lds_ptr = reinterpret_cast<__attribute__((address_space(3))) uint4*>(
      reinterpret_cast<uintptr_t>(l));
  auto* g_ptr = reinterpret_cast<const __attribute__((address_space(1))) uint4*>(
      reinterpret_cast<uintptr_t>(g));
  __builtin_amdgcn_global_load_lds(g_ptr, lds_ptr, 16, 0, 0);
}

// ws layout (bytes):
//   [0..159]              : dsinv[40] floats
//   [1024, 1024+98304)    : band B-frags (fp16 pairs), s-major, stored once:
//                           F=(s*3+n)*64+lane, uint4; dword t = (bmr, bmi) at
//                           f = s*16 + (lane>>4)*4 + t, k = n*16 + (lane&15)
//   [197632, 197632+16384): epi B-frags (fp16): E=(nt*4+ks)*64+lane, uint4
__global__ __launch_bounds__(256) void pv_prep(
    const float* __restrict__ bmr, const float* __restrict__ bmi,
    const float* __restrict__ c2pr, const float* __restrict__ c2pi,
    float* __restrict__ ws)
{
  const int tid = threadIdx.x;
  const int blk = blockIdx.x;
  if (blk == 0) {
    __shared__ float sds[256];
    int k = tid & 63, part = tid >> 6;
    float s = 0.f;
    if (k < NBAND_) {
      const float* col = bmr + k;
      #pragma unroll 16
      for (int f = part * 128; f < part * 128 + 128; f++) s += col[f * 40];
    }
    sds[tid] = s;
    __syncthreads();
    if (tid < NBAND_) {
      float t = sds[tid] + sds[tid + 64] + sds[tid + 128] + sds[tid + 192];
      ws[tid] = 1.0f / fmaxf(t, 1e-20f);
    }
  } else if (blk <= 24) {
    int F = (blk - 1) * 256 + tid;     // 0..6143
    int l = F & 63;
    int fid = F >> 6;                  // s*3 + n
    int s5 = fid / 3;
    int n = fid - s5 * 3;
    int k = n * 16 + (l & 15);
    int quad = l >> 4;
    unsigned dw[4];
    #pragma unroll
    for (int t2 = 0; t2 < 4; t2++) {
      float v0 = 0.f, v1 = 0.f;
      if (k < NBAND_) {
        int f = s5 * 16 + quad * 4 + t2;
        v0 = bmr[f * 40 + k]; v1 = bmi[f * 40 + k];
      }
      dw[t2] = pkhf(v0, v1);
    }
    ((uint4*)((char*)ws + 1024))[F] = make_uint4(dw[0], dw[1], dw[2], dw[3]);
  } else {
    int F2 = (blk - 25) * 256 + tid;   // 0..1023
    int lane = F2 & 63, E = F2 >> 6;
    int nt = E >> 2, ks = E & 3;
    int n = lane & 15, quad = lane >> 4;
    int p = nt * 16 + n;
    unsigned dw[4];
    #pragma unroll
    for (int t2 = 0; t2 < 4; t2++) {
      int c = ks * 16 + quad * 4 + t2;
      dw[t2] = pkhf(c2pr[p * 64 + c], -c2pi[p * 64 + c]);
    }
    ((uint4*)((char*)ws + 197632))[E * 64 + lane] = make_uint4(dw[0], dw[1], dw[2], dw[3]);
  }
}

// LDS dwords (total 10240 dw = 40,960 B -> 4 blocks/CU, all 800 resident):
//   vsh  uint[8][512] @0, XOR-chunk-swizzled: elem (c,f) at
//        c*512 + (((f>>2)^c)<<2) + (f&3)   -> conflict-free b128 reads
//   bst  uint4[2][768] @4096  -- B-frag double buffer (4 K-steps/stage)
//   epilogue overlay on vsh: bcsh uint[48][68]
__global__ __launch_bounds__(256, 4) void pv_main(
    const float* __restrict__ br, const float* __restrict__ bi,
    const float* __restrict__ ws, float* __restrict__ out)
{
  __shared__ __align__(16) unsigned smem[10240];
  unsigned* vsh = smem;                      // [8][512] fp16-pair, swizzled
  uint4*    bst = (uint4*)(smem + 4096);     // [2][768]

  const int bt  = blockIdx.x;
  const int tid = threadIdx.x;
  const float* pr  = br + (size_t)bt * (NCH_ * NBIN_);
  const float* pim = bi + (size_t)bt * (NCH_ * NBIN_);

  const int mt   = tid >> 6;       // wave id = M-tile
  const int lane = tid & 63;
  const int m16  = lane & 15;
  const int quad = lane >> 4;
  const int p    = mt * 16 + m16;
  const int ich  = p >> 3, jch = p & 7;
  const uint4* BF0 = (const uint4*)((const char*)ws + 1024);

  // ---- stage 0 DMA issued first: lands under phase A's compute ----
  {
    const uint4* g = BF0 + tid;
    uint4* l = bst + tid;
    gld_lds16(g, l);
    gld_lds16(g + 256, l + 256);
    gld_lds16(g + 512, l + 512);
  }

  // ---- phase A: 2 bins per thread -> vsh (fp16 pairs, swizzled) ----
  #pragma unroll
  for (int fs = 0; fs < 2; fs++) {
    const int f = fs * 256 + tid;
    const int fm = (f == 0) ? 0 : ((f == 511) ? 509 : f - 1);
    const int fp = (f == 0) ? 2 : ((f == 511) ? 511 : f + 1);
    float tr = 0.f;
    float t1[8], t2[8];
    #pragma unroll
    for (int c = 0; c < 8; c++) {
      const float* cr = pr + c * 512;
      const float* ci = pim + c * 512;
      float xr = cr[f],   xi = ci[f];
      float xrm = cr[fm], xim = ci[fm];
      float xrp = cr[fp], xip = ci[fp];
      tr = fmaf(xr, xr, tr); tr = fmaf(xi, xi, tr);
      float Gr = fmaf(xrm, xrp,  xim * xip);
      float Gi = fmaf(xrm, xip, -(xim * xrp));
      float am = fmaxf(fmaxf(fabsf(Gr), fabsf(Gi)), 1e-30f);
      float rc = __builtin_amdgcn_rcpf(am);
      float q1 = Gr * rc, q2 = Gi * rc;
      float n2 = fmaf(q1, q1, q2 * q2);
      float rn = __builtin_amdgcn_rsqf(n2);
      bool ok = n2 > 0.f;
      float ur = ok ? q1 * rn : 1.f;
      float ui = ok ? q2 * rn : 0.f;
      float mg = __builtin_amdgcn_sqrtf(fmaf(xr, xr, xi * xi));
      t1[c] = mg * ur; t2[c] = mg * ui;
    }
    float scv = __builtin_amdgcn_rsqf(fmaxf(tr, 1e-20f));
    const int fc = f >> 2, fl = f & 3;
    #pragma unroll
    for (int c = 0; c < 8; c++)
      vsh[c * 512 + ((fc ^ c) << 2) + fl] = pkhf(t1[c] * scv, t2[c] * scv);
  }
  __syncthreads();               // vsh ready AND stage-0 DMA drained

  // ---- band GEMM: 8 stages x 4 K-steps, B double-buffered in LDS ----
  const uint4* vb = (const uint4*)vsh;       // 128 chunks per channel

  float4v acc[6];                // [0..2]=real cols, [3..5]=imag cols
  #pragma unroll
  for (int g = 0; g < 6; g++) acc[g] = (float4v){0.f, 0.f, 0.f, 0.f};

  for (int st = 0; st < 8; st++) {
    if (st < 7) {                // DMA next stage into the other buffer
      const uint4* g = BF0 + (st + 1) * 768 + tid;
      uint4* l = bst + ((st + 1) & 1) * 768 + tid;
      gld_lds16(g, l);
      gld_lds16(g + 256, l + 256);
      gld_lds16(g + 512, l + 512);
    }
    const uint4* bb = bst + (st & 1) * 768;
    #pragma unroll
    for (int q = 0; q < 4; q++) {
      const int s = st * 4 + q;
      const int sc = s * 4 + quad;           // chunk index pre-swizzle
      uint4 av = vb[ich * 128 + (sc ^ ich)];
      uint4 bv = vb[jch * 128 + (sc ^ jch)];
      uint4 cb0 = bb[(q * 3 + 0) * 64 + lane];
      uint4 cb1 = bb[(q * 3 + 1) * 64 + lane];
      uint4 cb2 = bb[(q * 3 + 2) * 64 + lane];
      unsigned a0 = cmulc(av.x, bv.x);
      unsigned a1 = cmulc(av.y, bv.y);
      unsigned a2 = cmulc(av.z, bv.z);
      unsigned a3 = cmulc(av.w, bv.w);
      uint4 au1 = make_uint4(a0 ^ 0x80000000u, a1 ^ 0x80000000u,
                             a2 ^ 0x80000000u, a3 ^ 0x80000000u); // (ar, -ai)
      uint4 au2 = make_uint4(rot16(a0), rot16(a1),
                             rot16(a2), rot16(a3));               // (ai, ar)
      half8 af1 = __builtin_bit_cast(half8, au1);
      half8 af2 = __builtin_bit_cast(half8, au2);
      half8 b0 = __builtin_bit_cast(half8, cb0);
      half8 b1 = __builtin_bit_cast(half8, cb1);
      half8 b2 = __builtin_bit_cast(half8, cb2);
      acc[0] = __builtin_amdgcn_mfma_f32_16x16x32_f16(af1, b0, acc[0], 0, 0, 0);
      acc[3] = __builtin_amdgcn_mfma_f32_16x16x32_f16(af2, b0, acc[3], 0, 0, 0);
      acc[1] = __builtin_amdgcn_mfma_f32_16x16x32_f16(af1, b1, acc[1], 0, 0, 0);
      acc[4] = __builtin_amdgcn_mfma_f32_16x16x32_f16(af2, b1, acc[4], 0, 0, 0);
      acc[2] = __builtin_amdgcn_mfma_f32_16x16x32_f16(af1, b2, acc[2], 0, 0, 0);
      acc[5] = __builtin_amdgcn_mfma_f32_16x16x32_f16(af2, b2, acc[5], 0, 0, 0);
    }
    __syncthreads();             // drains next-stage DMA; guards buffer reuse
  }

  // ---- epilogue GEMM: pv[k][p] = Re(sum_c c2p[p][c]*bc[k][c]) ----
  const uint4* EF = ((const uint4*)((const char*)ws + 197632)) + (mt * 4) * 64 + lane;
  uint4 eb[4];
  #pragma unroll
  for (int ks = 0; ks < 4; ks++) eb[ks] = EF[ks * 64];

  unsigned* bcsh = smem;              // [48][68] fp16-pair, overlays vsh
  #pragma unroll
  for (int n = 0; n < 3; n++) {
    uint4 w4 = make_uint4(pkhf(acc[n][0], acc[n + 3][0]),
                          pkhf(acc[n][1], acc[n + 3][1]),
                          pkhf(acc[n][2], acc[n + 3][2]),
                          pkhf(acc[n][3], acc[n + 3][3]));
    *(uint4*)(bcsh + (n * 16 + m16) * 68 + mt * 16 + quad * 4) = w4;
  }
  __syncthreads();

  float4v eacc[3];
  #pragma unroll
  for (int kt = 0; kt < 3; kt++) eacc[kt] = (float4v){0.f, 0.f, 0.f, 0.f};
  #pragma unroll
  for (int ks = 0; ks < 4; ks++) {
    half8 bfr = __builtin_bit_cast(half8, eb[ks]);
    #pragma unroll
    for (int kt = 0; kt < 3; kt++) {
      uint4 a4 = *(const uint4*)(bcsh + (kt * 16 + m16) * 68 + ks * 16 + quad * 4);
      half8 afr = __builtin_bit_cast(half8, a4);
      eacc[kt] = __builtin_amdgcn_mfma_f32_16x16x32_f16(afr, bfr, eacc[kt], 0, 0, 0);
    }
  }
  float* op = out + (size_t)bt * (NBAND_ * NPV_);
  const float4* wsd = (const float4*)ws;   // dsinv[40]
  #pragma unroll
  for (int kt = 0; kt < 3; kt++) {
    float4 dv = wsd[kt * 4 + quad];
    float dva[4] = {dv.x, dv.y, dv.z, dv.w};
    #pragma unroll
    for (int r = 0; r < 4; r++) {
      int k = kt * 16 + quad * 4 + r;
      if (k < NBAND_)
        op[k * 64 + mt * 16 + m16] = eacc[kt][r] * dva[r];
    }
  }
}

// ---------------- IIR: chunked scan, 320 blocks x 256 thr, chunk=25 ----------------
__global__ __launch_bounds__(256) void pv_iir3(float* __restrict__ z,
                                               const float* __restrict__ tau)
{
  __shared__ float gsh[16][16];
  const int pg = blockIdx.x & 3;
  const int bk = blockIdx.x >> 2;
  const int k = bk % NBAND_;
  const int b = bk / NBAND_;
  const float a  = tau[k];
  const float om = 1.0f - a;
  const int c  = threadIdx.x >> 4;
  const int pl = threadIdx.x & 15;
  const int p  = pg * 16 + pl;
  const size_t stride = (size_t)NBAND_ * 64;
  size_t idx0 = (size_t)b * (T_ * NBAND_ * 64) + (size_t)(c * 25) * stride + k * 64 + p;

  float y[25];
  float accv = 0.f;
  #pragma unroll
  for (int i = 0; i < 25; i++) {
    float v = z[idx0 + (size_t)i * stride];
    accv = fmaf(a, accv, om * v);
    y[i] = accv;
  }
  gsh[c][pl] = accv;
  __syncthreads();
  float a2 = a * a, a8 = a2 * a2 * a2 * a2, a16 = a8 * a8;
  float A = a16 * a8 * a;                   // a^25
  float H = 0.f;
  #pragma unroll
  for (int d = 0; d < 15; d++) {
    if (d < c) H = fmaf(A, H, gsh[d][pl]);
  }
  float wp = a;
  #pragma unroll
  for (int i = 0; i < 25; i++) {
    z[idx0 + (size_t)i * stride] = fmaf(wp, H, y[i]);
    wp *= a;
  }
}

extern "C" void kernel_launch(void* const* d_in, const int* in_sizes, int n_in,
                              void* d_out, int out_size, void* d_ws, size_t ws_size,
                              hipStream_t stream)
{
  const float* br   = (const float*)d_in[0];
  const float* bi   = (const float*)d_in[1];
  const float* bmr  = (const float*)d_in[2];
  const float* bmi  = (const float*)d_in[3];
  const float* c2pr = (const float*)d_in[4];
  const float* c2pi = (const float*)d_in[5];
  const float* tau  = (const float*)d_in[6];
  float* out = (float*)d_out;
  float* ws  = (float*)d_ws;

  hipLaunchKernelGGL(pv_prep, dim3(29), dim3(256), 0, stream,
                     bmr, bmi, c2pr, c2pi, ws);
  hipLaunchKernelGGL(pv_main, dim3(B_ * T_), dim3(256), 0, stream,
                     br, bi, ws, out);
  hipLaunchKernelGGL(pv_iir3, dim3(B_ * NBAND_ * 4), dim3(256), 0, stream,
                     out, tau);
}

// Round 11
// 113.137 us; speedup vs baseline: 1.0588x; 1.0076x over previous
//
#include <hip/hip_runtime.h>
#include <hip/hip_fp16.h>

#define B_    2
#define T_    400
#define NCH_  8
#define NBIN_ 512
#define NBAND_ 40
#define NPV_  64

using half8   = __attribute__((ext_vector_type(8))) _Float16;
using float4v = __attribute__((ext_vector_type(4))) float;

// pack two floats into fp16 pair dword (lo=x, hi=y), RNE
static __device__ inline unsigned pkhf(float x, float y) {
  __half2 h = __float22half2_rn(make_float2(x, y));
  return __builtin_bit_cast(unsigned, h);
}
static __device__ inline unsigned rot16(unsigned u) {
  return (u >> 16) | (u << 16);
}
// packed complex multiply a = v_i * conj(v_j); dwords are (lo=re, hi=im)
static __device__ inline unsigned cmulc(unsigned viu, unsigned vju) {
  __half2 Vi = __builtin_bit_cast(__half2, viu);
  __half2 Vj = __builtin_bit_cast(__half2, vju);
  __half2 P1 = __hmul2(Vi, __low2half2(Vj));
  __half2 Qi = __lowhigh2highlow(Vi);
  unsigned tn = __builtin_bit_cast(unsigned, __high2half2(Vj)) ^ 0x80000000u;
  __half2 a  = __hfma2(Qi, __builtin_bit_cast(__half2, tn), P1);
  return __builtin_bit_cast(unsigned, a);
}
// async global->LDS DMA, 16 B per lane
static __device__ inline void gld_lds16(const uint4* g, uint4* l) {
  auto* lds_ptr = reinterpret_cast<__attribute__((address_space(3))) uint4*>(
      reinterpret_cast<uintptr_t>(l));
  auto* g_ptr = reinterpret_cast<const __attribute__((address_space(1))) uint4*>(
      reinterpret_cast<uintptr_t>(g));
  __builtin_amdgcn_global_load_lds(g_ptr, lds_ptr, 16, 0, 0);
}

// ws layout (bytes):
//   [0..159]              : dsinv[40] floats
//   [1024, 1024+98304)    : band B-frags (fp16 pairs), s-major, stored once:
//                           F=(s*3+n)*64+lane, uint4; dword t = (bmr, bmi) at
//                           f = s*16 + (lane>>4)*4 + t, k = n*16 + (lane&15)
//   [197632, 197632+16384): epi B-frags (fp16): E=(nt*4+ks)*64+lane, uint4
__global__ __launch_bounds__(256) void pv_prep(
    const float* __restrict__ bmr, const float* __restrict__ bmi,
    const float* __restrict__ c2pr, const float* __restrict__ c2pi,
    float* __restrict__ ws)
{
  const int tid = threadIdx.x;
  const int blk = blockIdx.x;
  if (blk == 0) {
    __shared__ float sds[256];
    int k = tid & 63, part = tid >> 6;
    float s = 0.f;
    if (k < NBAND_) {
      const float* col = bmr + k;
      #pragma unroll 16
      for (int f = part * 128; f < part * 128 + 128; f++) s += col[f * 40];
    }
    sds[tid] = s;
    __syncthreads();
    if (tid < NBAND_) {
      float t = sds[tid] + sds[tid + 64] + sds[tid + 128] + sds[tid + 192];
      ws[tid] = 1.0f / fmaxf(t, 1e-20f);
    }
  } else if (blk <= 24) {
    int F = (blk - 1) * 256 + tid;     // 0..6143
    int l = F & 63;
    int fid = F >> 6;                  // s*3 + n
    int s5 = fid / 3;
    int n = fid - s5 * 3;
    int k = n * 16 + (l & 15);
    int quad = l >> 4;
    unsigned dw[4];
    #pragma unroll
    for (int t2 = 0; t2 < 4; t2++) {
      float v0 = 0.f, v1 = 0.f;
      if (k < NBAND_) {
        int f = s5 * 16 + quad * 4 + t2;
        v0 = bmr[f * 40 + k]; v1 = bmi[f * 40 + k];
      }
      dw[t2] = pkhf(v0, v1);
    }
    ((uint4*)((char*)ws + 1024))[F] = make_uint4(dw[0], dw[1], dw[2], dw[3]);
  } else {
    int F2 = (blk - 25) * 256 + tid;   // 0..1023
    int lane = F2 & 63, E = F2 >> 6;
    int nt = E >> 2, ks = E & 3;
    int n = lane & 15, quad = lane >> 4;
    int p = nt * 16 + n;
    unsigned dw[4];
    #pragma unroll
    for (int t2 = 0; t2 < 4; t2++) {
      int c = ks * 16 + quad * 4 + t2;
      dw[t2] = pkhf(c2pr[p * 64 + c], -c2pi[p * 64 + c]);
    }
    ((uint4*)((char*)ws + 197632))[E * 64 + lane] = make_uint4(dw[0], dw[1], dw[2], dw[3]);
  }
}

// Two frames (bt) per block: B-frag LDS reads + DMA + barriers amortized 2x.
// LDS dwords (14336 dw = 57,344 B -> 2 blocks/CU, 400 blocks):
//   vsh0 uint[8][512] @0     (bt0, XOR-chunk swizzle (c,f): c*512+(((f>>2)^c)<<2)+(f&3))
//   vsh1 uint[8][512] @4096  (bt1)
//   bst  uint4[2][768] @8192 -- B-frag double buffer (4 K-steps/stage)
//   epilogue: bcsh uint[48][68] overlays each vsh region
__global__ __launch_bounds__(256, 2) void pv_main(
    const float* __restrict__ br, const float* __restrict__ bi,
    const float* __restrict__ ws, float* __restrict__ out)
{
  __shared__ __align__(16) unsigned smem[14336];
  unsigned* vshA[2] = { smem, smem + 4096 };
  uint4*    bst = (uint4*)(smem + 8192);     // [2][768]

  const int bt0 = blockIdx.x * 2;
  const int tid = threadIdx.x;

  const int mt   = tid >> 6;       // wave id = M-tile
  const int lane = tid & 63;
  const int m16  = lane & 15;
  const int quad = lane >> 4;
  const int p    = mt * 16 + m16;
  const int ich  = p >> 3, jch = p & 7;
  const uint4* BF0 = (const uint4*)((const char*)ws + 1024);

  // ---- stage 0 DMA issued first: lands under phase A's compute ----
  {
    const uint4* g = BF0 + tid;
    uint4* l = bst + tid;
    gld_lds16(g, l);
    gld_lds16(g + 256, l + 256);
    gld_lds16(g + 512, l + 512);
  }

  // ---- phase A: 2 bins per thread per frame -> vsh (fp16 pairs, swizzled) ----
  #pragma unroll
  for (int h = 0; h < 2; h++) {
    const float* pr  = br + (size_t)(bt0 + h) * (NCH_ * NBIN_);
    const float* pim = bi + (size_t)(bt0 + h) * (NCH_ * NBIN_);
    unsigned* vsh = vshA[h];
    #pragma unroll
    for (int fs = 0; fs < 2; fs++) {
      const int f = fs * 256 + tid;
      const int fm = (f == 0) ? 0 : ((f == 511) ? 509 : f - 1);
      const int fp = (f == 0) ? 2 : ((f == 511) ? 511 : f + 1);
      float tr = 0.f;
      float t1[8], t2[8];
      #pragma unroll
      for (int c = 0; c < 8; c++) {
        const float* cr = pr + c * 512;
        const float* ci = pim + c * 512;
        float xr = cr[f],   xi = ci[f];
        float xrm = cr[fm], xim = ci[fm];
        float xrp = cr[fp], xip = ci[fp];
        tr = fmaf(xr, xr, tr); tr = fmaf(xi, xi, tr);
        float Gr = fmaf(xrm, xrp,  xim * xip);
        float Gi = fmaf(xrm, xip, -(xim * xrp));
        float am = fmaxf(fmaxf(fabsf(Gr), fabsf(Gi)), 1e-30f);
        float rc = __builtin_amdgcn_rcpf(am);
        float q1 = Gr * rc, q2 = Gi * rc;
        float n2 = fmaf(q1, q1, q2 * q2);
        float rn = __builtin_amdgcn_rsqf(n2);
        bool ok = n2 > 0.f;
        float ur = ok ? q1 * rn : 1.f;
        float ui = ok ? q2 * rn : 0.f;
        float mg = __builtin_amdgcn_sqrtf(fmaf(xr, xr, xi * xi));
        t1[c] = mg * ur; t2[c] = mg * ui;
      }
      float scv = __builtin_amdgcn_rsqf(fmaxf(tr, 1e-20f));
      const int fc = f >> 2, fl = f & 3;
      #pragma unroll
      for (int c = 0; c < 8; c++)
        vsh[c * 512 + ((fc ^ c) << 2) + fl] = pkhf(t1[c] * scv, t2[c] * scv);
    }
  }
  __syncthreads();               // vsh ready AND stage-0 DMA drained

  // ---- band GEMM: 8 stages x 4 K-steps x 2 frames; B shared across frames ----
  float4v acc[12];               // [h*6+0..2]=real cols, [h*6+3..5]=imag cols
  #pragma unroll
  for (int g = 0; g < 12; g++) acc[g] = (float4v){0.f, 0.f, 0.f, 0.f};

  for (int st = 0; st < 8; st++) {
    if (st < 7) {                // DMA next stage into the other buffer
      const uint4* g = BF0 + (st + 1) * 768 + tid;
      uint4* l = bst + ((st + 1) & 1) * 768 + tid;
      gld_lds16(g, l);
      gld_lds16(g + 256, l + 256);
      gld_lds16(g + 512, l + 512);
    }
    const uint4* bb = bst + (st & 1) * 768;
    #pragma unroll
    for (int q = 0; q < 4; q++) {
      const int s = st * 4 + q;
      const int sc = s * 4 + quad;           // chunk index pre-swizzle
      uint4 cb0 = bb[(q * 3 + 0) * 64 + lane];
      uint4 cb1 = bb[(q * 3 + 1) * 64 + lane];
      uint4 cb2 = bb[(q * 3 + 2) * 64 + lane];
      half8 b0 = __builtin_bit_cast(half8, cb0);
      half8 b1 = __builtin_bit_cast(half8, cb1);
      half8 b2 = __builtin_bit_cast(half8, cb2);
      #pragma unroll
      for (int h = 0; h < 2; h++) {
        const uint4* vb = (const uint4*)vshA[h];
        uint4 av = vb[ich * 128 + (sc ^ ich)];
        uint4 bv = vb[jch * 128 + (sc ^ jch)];
        unsigned a0 = cmulc(av.x, bv.x);
        unsigned a1 = cmulc(av.y, bv.y);
        unsigned a2 = cmulc(av.z, bv.z);
        unsigned a3 = cmulc(av.w, bv.w);
        uint4 au1 = make_uint4(a0 ^ 0x80000000u, a1 ^ 0x80000000u,
                               a2 ^ 0x80000000u, a3 ^ 0x80000000u); // (ar, -ai)
        uint4 au2 = make_uint4(rot16(a0), rot16(a1),
                               rot16(a2), rot16(a3));               // (ai, ar)
        half8 af1 = __builtin_bit_cast(half8, au1);
        half8 af2 = __builtin_bit_cast(half8, au2);
        acc[h*6+0] = __builtin_amdgcn_mfma_f32_16x16x32_f16(af1, b0, acc[h*6+0], 0, 0, 0);
        acc[h*6+3] = __builtin_amdgcn_mfma_f32_16x16x32_f16(af2, b0, acc[h*6+3], 0, 0, 0);
        acc[h*6+1] = __builtin_amdgcn_mfma_f32_16x16x32_f16(af1, b1, acc[h*6+1], 0, 0, 0);
        acc[h*6+4] = __builtin_amdgcn_mfma_f32_16x16x32_f16(af2, b1, acc[h*6+4], 0, 0, 0);
        acc[h*6+2] = __builtin_amdgcn_mfma_f32_16x16x32_f16(af1, b2, acc[h*6+2], 0, 0, 0);
        acc[h*6+5] = __builtin_amdgcn_mfma_f32_16x16x32_f16(af2, b2, acc[h*6+5], 0, 0, 0);
      }
    }
    __syncthreads();             // drains next-stage DMA; guards buffer reuse
  }

  // ---- epilogue GEMM (both frames): pv[k][p] = Re(sum_c c2p[p][c]*bc[k][c]) ----
  const uint4* EF = ((const uint4*)((const char*)ws + 197632)) + (mt * 4) * 64 + lane;
  uint4 eb[4];
  #pragma unroll
  for (int ks = 0; ks < 4; ks++) eb[ks] = EF[ks * 64];

  #pragma unroll
  for (int h = 0; h < 2; h++) {
    unsigned* bcsh = vshA[h];          // [48][68] fp16-pair, overlays vsh
    #pragma unroll
    for (int n = 0; n < 3; n++) {
      uint4 w4 = make_uint4(pkhf(acc[h*6+n][0], acc[h*6+n+3][0]),
                            pkhf(acc[h*6+n][1], acc[h*6+n+3][1]),
                            pkhf(acc[h*6+n][2], acc[h*6+n+3][2]),
                            pkhf(acc[h*6+n][3], acc[h*6+n+3][3]));
      *(uint4*)(bcsh + (n * 16 + m16) * 68 + mt * 16 + quad * 4) = w4;
    }
  }
  __syncthreads();

  const float4* wsd = (const float4*)ws;   // dsinv[40]
  #pragma unroll
  for (int h = 0; h < 2; h++) {
    const unsigned* bcsh = vshA[h];
    float4v eacc[3];
    #pragma unroll
    for (int kt = 0; kt < 3; kt++) eacc[kt] = (float4v){0.f, 0.f, 0.f, 0.f};
    #pragma unroll
    for (int ks = 0; ks < 4; ks++) {
      half8 bfr = __builtin_bit_cast(half8, eb[ks]);
      #pragma unroll
      for (int kt = 0; kt < 3; kt++) {
        uint4 a4 = *(const uint4*)(bcsh + (kt * 16 + m16) * 68 + ks * 16 + quad * 4);
        half8 afr = __builtin_bit_cast(half8, a4);
        eacc[kt] = __builtin_amdgcn_mfma_f32_16x16x32_f16(afr, bfr, eacc[kt], 0, 0, 0);
      }
    }
    float* op = out + (size_t)(bt0 + h) * (NBAND_ * NPV_);
    #pragma unroll
    for (int kt = 0; kt < 3; kt++) {
      float4 dv = wsd[kt * 4 + quad];
      float dva[4] = {dv.x, dv.y, dv.z, dv.w};
      #pragma unroll
      for (int r = 0; r < 4; r++) {
        int k = kt * 16 + quad * 4 + r;
        if (k < NBAND_)
          op[k * 64 + mt * 16 + m16] = eacc[kt][r] * dva[r];
      }
    }
  }
}

// ---------------- IIR: chunked scan, chunk=10, 320 blocks x 640 thr ----------------
// 3200 waves (2.5x R10) for latency hiding; combine = 39-deep predicated fma fold.
__global__ __launch_bounds__(640) void pv_iir4(float* __restrict__ z,
                                               const float* __restrict__ tau)
{
  __shared__ float gsh[40][16];
  const int pg = blockIdx.x & 3;
  const int bk = blockIdx.x >> 2;            // 0..79 = b*40+k
  const int k = bk % NBAND_;
  const int b = bk / NBAND_;
  const float a  = tau[k];
  const float om = 1.0f - a;
  const int c  = threadIdx.x >> 4;           // chunk 0..39
  const int pl = threadIdx.x & 15;
  const int p  = pg * 16 + pl;
  const size_t stride = (size_t)NBAND_ * 64;
  size_t idx0 = (size_t)b * (T_ * NBAND_ * 64) + (size_t)(c * 10) * stride + k * 64 + p;

  float y[10];
  float accv = 0.f;
  #pragma unroll
  for (int i = 0; i < 10; i++) {
    float v = z[idx0 + (size_t)i * stride];
    accv = fmaf(a, accv, om * v);
    y[i] = accv;
  }
  gsh[c][pl] = accv;
  __syncthreads();
  float a2 = a * a, a4 = a2 * a2, a8 = a4 * a4;
  float A = a8 * a2;                         // a^10
  float H = 0.f;
  #pragma unroll
  for (int d = 0; d < 39; d++) {
    float g = gsh[d][pl];
    H = (d < c) ? fmaf(A, H, g) : H;
  }
  float wp = a;
  #pragma unroll
  for (int i = 0; i < 10; i++) {
    z[idx0 + (size_t)i * stride] = fmaf(wp, H, y[i]);
    wp *= a;
  }
}

extern "C" void kernel_launch(void* const* d_in, const int* in_sizes, int n_in,
                              void* d_out, int out_size, void* d_ws, size_t ws_size,
                              hipStream_t stream)
{
  const float* br   = (const float*)d_in[0];
  const float* bi   = (const float*)d_in[1];
  const float* bmr  = (const float*)d_in[2];
  const float* bmi  = (const float*)d_in[3];
  const float* c2pr = (const float*)d_in[4];
  const float* c2pi = (const float*)d_in[5];
  const float* tau  = (const float*)d_in[6];
  float* out = (float*)d_out;
  float* ws  = (float*)d_ws;

  hipLaunchKernelGGL(pv_prep, dim3(29), dim3(256), 0, stream,
                     bmr, bmi, c2pr, c2pi, ws);
  hipLaunchKernelGGL(pv_main, dim3(B_ * T_ / 2), dim3(256), 0, stream,
                     br, bi, ws, out);
  hipLaunchKernelGGL(pv_iir4, dim3(B_ * NBAND_ * 4), dim3(640), 0, stream,
                     out, tau);
}